// Round 12
// baseline (9868.507 us; speedup 1.0000x reference)
//
#include <hip/hip_runtime.h>
#include <hip/hip_bf16.h>
#include <stdint.h>

// ---------------------------------------------------------------------------
// 2-layer GRU (B=64,T=512,IN=256,H=1024) + FC, fp32 I/O.
// R12 = R11 with the layer-0 W_ih LDS-staging loop restored verbatim from R9
// (R10/R11's `if (tid<768)` only covered f=0..511 of 768 fragments -> W_ihN
// never staged -> NaN. One-line class of bug; everything else unchanged.)
//   - R9 compute: W in LDS, in-WG K-split, counted-vmcnt asm rings. [PASSED]
//   - per-XCD A-staging: coherent L3 -> local L2, sc0 compute loads. [R6 PASSED]
//   - ALL sync agent-scope (L3): local staging barrier + flat global barrier.
// Precision: W bf16, h as bf16 hi+lo planes, gates fp32.
// ---------------------------------------------------------------------------

constexpr int TSEQ = 512;
constexpr int NB   = 64;
constexpr int HD   = 1024;
constexpr int IND  = 256;
constexpr int NWG  = 256;
constexpr int FS   = 16;            // counter stride in ints (64B lines)
constexpr int PL   = NB * HD;       // elements per h plane
constexpr int CHT  = 4 * PL / 8;    // staged 16B chunks per XCD (32768)

typedef float f32x4  __attribute__((ext_vector_type(4)));
typedef short short8 __attribute__((ext_vector_type(8)));

__device__ __forceinline__ float bf2f(unsigned u) {
    return __builtin_bit_cast(float, u << 16);
}
__device__ __forceinline__ unsigned short f2bf(float f) {
    unsigned u = __builtin_bit_cast(unsigned, f);
    u += 0x7fffu + ((u >> 16) & 1u);     // RNE
    return (unsigned short)(u >> 16);
}
__device__ __forceinline__ float sigm(float x) { return 1.0f / (1.0f + __expf(-x)); }
__device__ __forceinline__ float tanh_fast(float x) { return 1.0f - 2.0f / (1.0f + __expf(2.0f * x)); }

__device__ __forceinline__ void cstore16(unsigned short* p, unsigned short v) {
    __hip_atomic_store(p, v, __ATOMIC_RELAXED, __HIP_MEMORY_SCOPE_AGENT);
}
__device__ __forceinline__ unsigned short cload16(const unsigned short* p) {
    return __hip_atomic_load(p, __ATOMIC_RELAXED, __HIP_MEMORY_SCOPE_AGENT);
}

#define MFMA(a, b, c) __builtin_amdgcn_mfma_f32_16x16x32_bf16((a), (b), (c), 0, 0, 0)

// Coherent L3 load (staging copy), 16B.
#define LDC16(dst, ptr) \
    asm volatile("global_load_dwordx4 %0, %1, off sc0 sc1" : "=v"(dst) : "v"(ptr))
// XCD-local staged A-load: bypass L1, hit local L2.
#define LDB16(dst, base, imm) \
    asm volatile("global_load_dwordx4 %0, %1, off offset:%2 sc0" \
                 : "=v"(dst) : "v"(base), "i"(imm))
// Plain cached 16B load (x input).
#define LDX16(dst, base, imm) \
    asm volatile("global_load_dwordx4 %0, %1, off offset:%2" \
                 : "=v"(dst) : "v"(base), "i"(imm))
#define VWAIT(n) do { asm volatile("s_waitcnt vmcnt(" #n ")" ::: "memory"); \
                      __builtin_amdgcn_sched_barrier(0); } while (0)

__global__ void convert_w(const float* __restrict__ src, unsigned short* __restrict__ dst, int n) {
    int i = blockIdx.x * blockDim.x + threadIdx.x;
    int stride = gridDim.x * blockDim.x;
    for (; i < n; i += stride) dst[i] = f2bf(src[i]);
}

__global__ __launch_bounds__(512, 2) void gru_main(
    const float* __restrict__ x,
    const unsigned short* __restrict__ wih0,
    const unsigned short* __restrict__ whh0,
    const unsigned short* __restrict__ wih1,
    const unsigned short* __restrict__ whh1,
    const float* __restrict__ bih0, const float* __restrict__ bhh0,
    const float* __restrict__ bih1, const float* __restrict__ bhh1,
    const float* __restrict__ wfc,  const float* __restrict__ bfc,
    unsigned short* __restrict__ h0hi, unsigned short* __restrict__ h0lo,
    unsigned short* __restrict__ h1hi, unsigned short* __restrict__ h1lo,
    unsigned short* __restrict__ stg,
    int* __restrict__ larr, int* __restrict__ arrive,
    int* __restrict__ xcnt, int* __restrict__ regcnt,
    float* __restrict__ out)
{
    const int wg    = blockIdx.x;
    const int layer = wg >> 7;           // 0 / 1
    const int cc    = wg & 127;          // 8-col chunk
    const int jb8   = cc << 3;
    const int tid   = threadIdx.x;
    const int wid   = tid >> 6;          // 0..7
    const int kh    = wid >> 2;          // K-half
    const int mw    = wid & 3;           // M-tile
    const int lane  = tid & 63;
    const int l15   = lane & 15;
    const int c8    = l15 & 7;           // real col (lanes 8-15 duplicate)
    const int kg8   = (lane >> 4) << 3;
    const int arow  = (mw << 4) + l15;
    const int kb    = kh << 9;           // recurrent K base (elements)
    const int ckb   = kh << 4;           // k-chunk base (chunks of 32)
    const int kbx   = kh << 7;           // L0 input K base

    const unsigned short* Whh = layer ? whh1 : whh0;
    const unsigned short* Wih = layer ? wih1 : wih0;
    const float* bih = layer ? bih1 : bih0;
    const float* bhh = layer ? bhh1 : bhh0;
    unsigned short* hhi = layer ? h1hi : h0hi;
    unsigned short* hlo = layer ? h1lo : h0lo;

    const int jg = jb8 + c8;

    const float bias_r  = bih[jg]        + bhh[jg];
    const float bias_z  = bih[HD + jg]   + bhh[HD + jg];
    const float bias_nx = bih[2*HD + jg];
    const float bias_nh = bhh[2*HD + jg];

    __shared__ unsigned short wlds[192 * 256];   // 96KB W tile
    __shared__ float part[16 * 4 * 64];          // 16KB K-half exchange
    __shared__ float red[256];
    __shared__ int sh_rank, sh_ng;

    // ---- one-time W staging into LDS (R9 layout + R9 loop, verbatim) ----
    if (layer == 1) {
        #pragma unroll
        for (int i = 0; i < 12; ++i) {
            int f = tid + i * 512;
            int s   = f >> 10;
            int rem = f & 1023;
            int ck  = rem >> 5;
            int hi  = (rem >> 3) & 3;
            int c   = rem & 7;
            const unsigned short* src = (s < 3 ? Whh : Wih)
                + (size_t)((s % 3) * HD + jb8 + c) * HD + ck * 32 + hi * 8;
            *(short8*)(wlds + (s * 32 + ck) * 256 + hi * 64 + c * 8) =
                *(const short8*)src;
        }
    } else {
        #pragma unroll
        for (int i = 0; i < 6; ++i) {
            int f = tid + i * 512;
            int s   = f >> 10;
            int rem = f & 1023;
            int ck  = rem >> 5;
            int hi  = (rem >> 3) & 3;
            int c   = rem & 7;
            const unsigned short* src = Whh
                + (size_t)(s * HD + jb8 + c) * HD + ck * 32 + hi * 8;
            *(short8*)(wlds + (s * 32 + ck) * 256 + hi * 64 + c * 8) =
                *(const short8*)src;
        }
        for (int i = 0; i < 2; ++i) {            // f = 0..1023, clipped to 768
            int f = tid + i * 512;
            if (f < 768) {
                int s   = f >> 8;
                int rem = f & 255;
                int ck  = rem >> 5;
                int hi  = (rem >> 3) & 3;
                int c   = rem & 7;
                const unsigned short* src = Wih
                    + (size_t)(s * HD + jb8 + c) * IND + ck * 32 + hi * 8;
                *(short8*)(wlds + (96 + s * 8 + ck) * 256 + hi * 64 + c * 8) =
                    *(const short8*)src;
            }
        }
    }

    // ---- XCD identity + per-XCD registration (agent scope, R6-proven) ----
    unsigned xcd;
    asm("s_getreg_b32 %0, hwreg(HW_REG_XCC_ID)" : "=s"(xcd));
    xcd &= 7;
    unsigned short* stx = stg + (size_t)xcd * 4 * PL;
    if (tid == 0) {
        sh_rank = __hip_atomic_fetch_add(&xcnt[xcd * FS], 1,
                                         __ATOMIC_RELAXED, __HIP_MEMORY_SCOPE_AGENT);
        __hip_atomic_fetch_add(regcnt, 1, __ATOMIC_RELAXED, __HIP_MEMORY_SCOPE_AGENT);
        int spins = 0;
        while (__hip_atomic_load(regcnt, __ATOMIC_RELAXED,
                                 __HIP_MEMORY_SCOPE_AGENT) < NWG) {
            __builtin_amdgcn_s_sleep(1);
            if (++spins > (1 << 20)) break;
        }
        sh_ng = __hip_atomic_load(&xcnt[xcd * FS], __ATOMIC_RELAXED,
                                  __HIP_MEMORY_SCOPE_AGENT);
    }
    __syncthreads();
    const int rank = sh_rank;
    const int ng   = sh_ng;
    const int slice = (CHT + ng - 1) / ng;

    // Iteration-invariant staged A bases.
    // Planes: 0=S0hi=h0(prev).hi  1=S0lo  2=S1hi=h1(prev).hi  3=S1lo
    const unsigned short *bAh, *bAl, *bAy = nullptr;
    if (layer == 0) {
        bAh = stx + 0 * PL + (size_t)arow * HD + kb + kg8;
        bAl = stx + 1 * PL + (size_t)arow * HD + kb + kg8;
    } else {
        bAh = stx + 2 * PL + (size_t)arow * HD + kb + kg8;
        bAl = stx + 3 * PL + (size_t)arow * HD + kb + kg8;
        bAy = stx + 0 * PL + (size_t)arow * HD + kb + kg8;
    }

    const int lws = (lane >> 4) * 64 + c8 * 8;
#define LW(blk) (*(const short8*)(wlds + (blk) * 256 + lws))

    float hold[4] = {0.f, 0.f, 0.f, 0.f};

    for (int iter = 0; iter <= TSEQ; ++iter) {
        // ======== staging copy: coherent L3 -> local L2 (all WGs of XCD) ====
        {
            const unsigned short* c0 = h0hi + ((iter + 1) & 1) * PL;
            const unsigned short* c1 = h0lo + ((iter + 1) & 1) * PL;
            const unsigned short* c2 = h1hi + (iter & 1) * PL;
            const unsigned short* c3 = h1lo + (iter & 1) * PL;
            const int p0 = rank * slice;
            const int p1 = (p0 + slice < CHT) ? (p0 + slice) : CHT;
            for (int base = p0; base < p1; base += 512) {
                int f = base + tid;
                f = (f < p1) ? f : (p1 - 1);           // duplicate-safe clamp
                const int pl = f >> 13;
                const int q  = f & 8191;
                const unsigned short* s =
                    (pl == 0) ? c0 : (pl == 1) ? c1 : (pl == 2) ? c2 : c3;
                short8 v;
                LDC16(v, s + (size_t)q * 8);
                VWAIT(0);
                *(short8*)(stx + (size_t)pl * PL + (size_t)q * 8) = v;
            }
        }
        asm volatile("s_waitcnt vmcnt(0)" ::: "memory");   // staged data in L2
        __syncthreads();
        // ---- XCD-local staging barrier (AGENT scope — R6-proven) ----
        if (tid == 0) {
            int* lp = larr + ((size_t)iter * 8 + xcd) * FS;
            atomicAdd(lp, 1);
            int spins = 0;
            while (__hip_atomic_load(lp, __ATOMIC_RELAXED,
                                     __HIP_MEMORY_SCOPE_AGENT) < ng) {
                __builtin_amdgcn_s_sleep(1);
                if (++spins > (1 << 20)) break;        // fail loud, never hang
            }
        }
        __syncthreads();

        // ======== compute (R9 pipelines; A from local L2) ========
        const bool active = layer ? (iter >= 1) : (iter < TSEQ);
        if (active) {
            const int t     = layer ? (iter - 1) : iter;
            const int wslot = t & 1;

            f32x4 ar  = {0.f, 0.f, 0.f, 0.f};
            f32x4 az  = {0.f, 0.f, 0.f, 0.f};
            f32x4 ahn = {0.f, 0.f, 0.f, 0.f};
            f32x4 axn = {0.f, 0.f, 0.f, 0.f};

            if (layer == 0) {
                const float* px = x + ((size_t)arow * TSEQ + t) * IND + kbx + kg8;
                short8 Ah[5], Al[5], Wa[3], Wb[3];
#define L0A(c) do { LDB16(Ah[(c)%5], bAh, (c)*64); LDB16(Al[(c)%5], bAl, (c)*64); } while (0)
#define L0X(c) do { LDX16(Ah[(c)%5], px, ((c)-16)*128); LDX16(Al[(c)%5], px, ((c)-16)*128+16); } while (0)
#define WR0(c, WB) do { WB[0] = LW(ckb + (c)); WB[1] = LW(32 + ckb + (c)); \
                        WB[2] = LW(64 + ckb + (c)); } while (0)
#define WX0(c, WB) do { int xck = (ckb >> 2) + (c) - 16; \
                        WB[0] = LW(96 + xck); WB[1] = LW(104 + xck); \
                        WB[2] = LW(112 + xck); } while (0)
#define MR0(c, WB) do { \
    ar  = MFMA(Ah[(c)%5], WB[0], ar);  ar  = MFMA(Al[(c)%5], WB[0], ar);  \
    az  = MFMA(Ah[(c)%5], WB[1], az);  az  = MFMA(Al[(c)%5], WB[1], az);  \
    ahn = MFMA(Ah[(c)%5], WB[2], ahn); ahn = MFMA(Al[(c)%5], WB[2], ahn); } while (0)
#define MX0(c, WB) do { \
    float4 xa = __builtin_bit_cast(float4, Ah[(c)%5]); \
    float4 xc = __builtin_bit_cast(float4, Al[(c)%5]); \
    short8 af; \
    af[0] = (short)f2bf(xa.x); af[1] = (short)f2bf(xa.y); \
    af[2] = (short)f2bf(xa.z); af[3] = (short)f2bf(xa.w); \
    af[4] = (short)f2bf(xc.x); af[5] = (short)f2bf(xc.y); \
    af[6] = (short)f2bf(xc.z); af[7] = (short)f2bf(xc.w); \
    ar  = MFMA(af, WB[0], ar); \
    az  = MFMA(af, WB[1], az); \
    axn = MFMA(af, WB[2], axn); } while (0)
                WR0(0, Wa);
                L0A(0); L0A(1); L0A(2); L0A(3);
                WR0(1,  Wb); L0A(4);  VWAIT(8); MR0(0,  Wa);
                WR0(2,  Wa); L0A(5);  VWAIT(8); MR0(1,  Wb);
                WR0(3,  Wb); L0A(6);  VWAIT(8); MR0(2,  Wa);
                WR0(4,  Wa); L0A(7);  VWAIT(8); MR0(3,  Wb);
                WR0(5,  Wb); L0A(8);  VWAIT(8); MR0(4,  Wa);
                WR0(6,  Wa); L0A(9);  VWAIT(8); MR0(5,  Wb);
                WR0(7,  Wb); L0A(10); VWAIT(8); MR0(6,  Wa);
                WR0(8,  Wa); L0A(11); VWAIT(8); MR0(7,  Wb);
                WR0(9,  Wb); L0A(12); VWAIT(8); MR0(8,  Wa);
                WR0(10, Wa); L0A(13); VWAIT(8); MR0(9,  Wb);
                WR0(11, Wb); L0A(14); VWAIT(8); MR0(10, Wa);
                WR0(12, Wa); L0A(15); VWAIT(8); MR0(11, Wb);
                WR0(13, Wb); L0X(16); VWAIT(8); MR0(12, Wa);
                WR0(14, Wa); L0X(17); VWAIT(8); MR0(13, Wb);
                WR0(15, Wb); L0X(18); VWAIT(8); MR0(14, Wa);
                WX0(16, Wa); L0X(19); VWAIT(8); MR0(15, Wb);
                WX0(17, Wb); VWAIT(6); MX0(16, Wa);
                WX0(18, Wa); VWAIT(4); MX0(17, Wb);
                WX0(19, Wb); VWAIT(2); MX0(18, Wa);
                             VWAIT(0); MX0(19, Wb);
            } else {
                short8 Ah[5], Al[5], Ay[5], Wa[6], Wb[6];
#define L1A(c) do { LDB16(Ah[(c)%5], bAh, (c)*64); LDB16(Al[(c)%5], bAl, (c)*64); \
                    LDB16(Ay[(c)%5], bAy, (c)*64); } while (0)
#define WR1(c, WB) do { WB[0] = LW(ckb + (c)); WB[1] = LW(32 + ckb + (c)); \
    WB[2] = LW(64 + ckb + (c)); WB[3] = LW(96 + ckb + (c)); \
    WB[4] = LW(128 + ckb + (c)); WB[5] = LW(160 + ckb + (c)); } while (0)
#define MF1(c, WB) do { \
    ar  = MFMA(Ah[(c)%5], WB[0], ar);  ar  = MFMA(Al[(c)%5], WB[0], ar);  \
    ar  = MFMA(Ay[(c)%5], WB[3], ar); \
    az  = MFMA(Ah[(c)%5], WB[1], az);  az  = MFMA(Al[(c)%5], WB[1], az);  \
    az  = MFMA(Ay[(c)%5], WB[4], az); \
    ahn = MFMA(Ah[(c)%5], WB[2], ahn); ahn = MFMA(Al[(c)%5], WB[2], ahn); \
    axn = MFMA(Ay[(c)%5], WB[5], axn); } while (0)
                WR1(0, Wa);
                L1A(0); L1A(1); L1A(2); L1A(3);
                WR1(1,  Wb); L1A(4);  VWAIT(12); MF1(0,  Wa);
                WR1(2,  Wa); L1A(5);  VWAIT(12); MF1(1,  Wb);
                WR1(3,  Wb); L1A(6);  VWAIT(12); MF1(2,  Wa);
                WR1(4,  Wa); L1A(7);  VWAIT(12); MF1(3,  Wb);
                WR1(5,  Wb); L1A(8);  VWAIT(12); MF1(4,  Wa);
                WR1(6,  Wa); L1A(9);  VWAIT(12); MF1(5,  Wb);
                WR1(7,  Wb); L1A(10); VWAIT(12); MF1(6,  Wa);
                WR1(8,  Wa); L1A(11); VWAIT(12); MF1(7,  Wb);
                WR1(9,  Wb); L1A(12); VWAIT(12); MF1(8,  Wa);
                WR1(10, Wa); L1A(13); VWAIT(12); MF1(9,  Wb);
                WR1(11, Wb); L1A(14); VWAIT(12); MF1(10, Wa);
                WR1(12, Wa); L1A(15); VWAIT(12); MF1(11, Wb);
                WR1(13, Wb); VWAIT(9); MF1(12, Wa);
                WR1(14, Wa); VWAIT(6); MF1(13, Wb);
                WR1(15, Wb); VWAIT(3); MF1(14, Wa);
                             VWAIT(0); MF1(15, Wb);
            }

            // ---- K-half combine in LDS; gates + h store on kh0 waves ----
            if (kh) {
                #pragma unroll
                for (int e = 0; e < 4; ++e) {
                    part[((0*4 + e) * 4 + mw) * 64 + lane] = ar[e];
                    part[((1*4 + e) * 4 + mw) * 64 + lane] = az[e];
                    part[((2*4 + e) * 4 + mw) * 64 + lane] = ahn[e];
                    part[((3*4 + e) * 4 + mw) * 64 + lane] = axn[e];
                }
            }
            __syncthreads();
            if (!kh) {
                unsigned short* hwhi = hhi + wslot * PL;
                unsigned short* hwlo = hlo + wslot * PL;
                #pragma unroll
                for (int e = 0; e < 4; ++e) {
                    const float arr = ar[e]  + part[((0*4 + e) * 4 + mw) * 64 + lane];
                    const float azz = az[e]  + part[((1*4 + e) * 4 + mw) * 64 + lane];
                    const float ahh = ahn[e] + part[((2*4 + e) * 4 + mw) * 64 + lane];
                    const float axx = axn[e] + part[((3*4 + e) * 4 + mw) * 64 + lane];
                    const int bat = (mw << 4) + ((lane >> 4) << 2) + e;
                    const size_t idx = (size_t)bat * HD + jg;
                    float r = sigm(arr + bias_r);
                    float z = sigm(azz + bias_z);
                    float n = tanh_fast(axx + bias_nx + r * (ahh + bias_nh));
                    float hnew = (1.0f - z) * n + z * hold[e];
                    hold[e] = hnew;
                    if (l15 < 8) {
                        unsigned short hi_ = f2bf(hnew);
                        cstore16(hwhi + idx, hi_);
                        cstore16(hwlo + idx, f2bf(hnew - bf2f((unsigned)hi_)));
                    }
                }
            }
        }

        // ---- flat global barrier (agent scope, R9-proven) ----
        asm volatile("s_waitcnt vmcnt(0)" ::: "memory");   // h stores at L3
        __syncthreads();
        if (tid == 0) {
            atomicAdd(&arrive[(size_t)iter * FS], 1);
            int spins = 0;
            while (__hip_atomic_load(&arrive[(size_t)iter * FS],
                                     __ATOMIC_RELAXED, __HIP_MEMORY_SCOPE_AGENT) < NWG) {
                __builtin_amdgcn_s_sleep(1);
                if (++spins > (1 << 20)) break;   // fail loud, never hang
            }
        }
        __syncthreads();
    }

    // ---- deterministic FC tail (single WG, coherent reads) ----
    if (wg == 0) {
        const int fslot = (TSEQ - 1) & 1;
        const unsigned short* hf_hi = h1hi + (size_t)fslot * PL;
        const unsigned short* hf_lo = h1lo + (size_t)fslot * PL;
        if (tid < 256) {
            const int bat  = tid & 63;
            const int pidx = tid >> 6;
            const int k0   = pidx * (HD / 4);
            float s = 0.0f;
            for (int k = 0; k < HD / 4; ++k) {
                size_t idx = (size_t)bat * HD + k0 + k;
                s += (bf2f((unsigned)cload16(hf_hi + idx)) +
                      bf2f((unsigned)cload16(hf_lo + idx))) * wfc[k0 + k];
            }
            red[tid] = s;
        }
        __syncthreads();
        if (tid < 64)
            out[tid] = red[tid] + red[tid + 64] + red[tid + 128] + red[tid + 192] + bfc[0];
    }
}

extern "C" void kernel_launch(void* const* d_in, const int* in_sizes, int n_in,
                              void* d_out, int out_size, void* d_ws, size_t ws_size,
                              hipStream_t stream) {
    const float* x    = (const float*)d_in[0];
    const float* Wih0 = (const float*)d_in[1];
    const float* Whh0 = (const float*)d_in[2];
    const float* bih0 = (const float*)d_in[3];
    const float* bhh0 = (const float*)d_in[4];
    const float* Wih1 = (const float*)d_in[5];
    const float* Whh1 = (const float*)d_in[6];
    const float* bih1 = (const float*)d_in[7];
    const float* bhh1 = (const float*)d_in[8];
    const float* Wfc  = (const float*)d_in[9];
    const float* bfc  = (const float*)d_in[10];
    float* out = (float*)d_out;

    char* ws = (char*)d_ws;
    size_t off = 0;
    int* arrive = (int*)(ws + off); off += (size_t)(TSEQ + 1) * FS * 4;
    int* larr   = (int*)(ws + off); off += (size_t)(TSEQ + 1) * 8 * FS * 4;
    int* xcnt   = (int*)(ws + off); off += (size_t)8 * FS * 4;
    int* regcnt = (int*)(ws + off); off += (size_t)FS * 4;
    unsigned short* h0hi = (unsigned short*)(ws + off); off += (size_t)2 * PL * 2;
    unsigned short* h0lo = (unsigned short*)(ws + off); off += (size_t)2 * PL * 2;
    unsigned short* h1hi = (unsigned short*)(ws + off); off += (size_t)2 * PL * 2;
    unsigned short* h1lo = (unsigned short*)(ws + off); off += (size_t)2 * PL * 2;
    size_t zero_bytes = off;
    unsigned short* stg = (unsigned short*)(ws + off); off += (size_t)8 * 4 * PL * 2;
    unsigned short* wih0b = (unsigned short*)(ws + off); off += (size_t)3 * HD * IND * 2;
    unsigned short* whh0b = (unsigned short*)(ws + off); off += (size_t)3 * HD * HD * 2;
    unsigned short* wih1b = (unsigned short*)(ws + off); off += (size_t)3 * HD * HD * 2;
    unsigned short* whh1b = (unsigned short*)(ws + off); off += (size_t)3 * HD * HD * 2;
    if (off > ws_size) return;   // loud validation failure

    hipMemsetAsync(d_ws, 0, zero_bytes, stream);
    hipMemsetAsync(d_out, 0, (size_t)out_size * sizeof(float), stream);

    convert_w<<<512, 256, 0, stream>>>(Wih0, wih0b, 3 * HD * IND);
    convert_w<<<512, 256, 0, stream>>>(Whh0, whh0b, 3 * HD * HD);
    convert_w<<<512, 256, 0, stream>>>(Wih1, wih1b, 3 * HD * HD);
    convert_w<<<512, 256, 0, stream>>>(Whh1, whh1b, 3 * HD * HD);

    gru_main<<<NWG, 512, 0, stream>>>(x, wih0b, whh0b, wih1b, whh1b,
                                      bih0, bhh0, bih1, bhh1, Wfc, bfc,
                                      h0hi, h0lo, h1hi, h1lo, stg,
                                      larr, arrive, xcnt, regcnt, out);
}

// Round 13
// 7107.677 us; speedup vs baseline: 1.3884x; 1.3884x over previous
//
#include <hip/hip_runtime.h>
#include <hip/hip_bf16.h>
#include <stdint.h>

// ---------------------------------------------------------------------------
// 2-layer GRU (B=64,T=512,IN=256,H=1024) + FC, fp32 I/O.
// R13 = R9 (PASSED, 8.59ms) with ONLY the global barrier replaced:
//   flat 256-way single-line counter (self-jamming: 256 RMWs + ~250 pollers
//   saturate one L3 slice)  -->  3-level agent-scope tree:
//   32 group counters (8 WGs, last arriver leads) -> 1 root counter
//   (32 leaders) -> root fans out 32 per-group release lines (8 pollers each).
// Per-XCD staging dropped (R12 falsified: no compute gain, +2.5us overhead).
// Precision: W bf16, h as bf16 hi+lo planes, gates fp32.
// ---------------------------------------------------------------------------

constexpr int TSEQ = 512;
constexpr int NB   = 64;
constexpr int HD   = 1024;
constexpr int IND  = 256;
constexpr int NWG  = 256;
constexpr int FS   = 16;            // counter stride in ints (64B lines)
constexpr int PL   = NB * HD;       // elements per h plane

typedef float f32x4  __attribute__((ext_vector_type(4)));
typedef short short8 __attribute__((ext_vector_type(8)));

__device__ __forceinline__ float bf2f(unsigned u) {
    return __builtin_bit_cast(float, u << 16);
}
__device__ __forceinline__ unsigned short f2bf(float f) {
    unsigned u = __builtin_bit_cast(unsigned, f);
    u += 0x7fffu + ((u >> 16) & 1u);     // RNE
    return (unsigned short)(u >> 16);
}
__device__ __forceinline__ float sigm(float x) { return 1.0f / (1.0f + __expf(-x)); }
__device__ __forceinline__ float tanh_fast(float x) { return 1.0f - 2.0f / (1.0f + __expf(2.0f * x)); }

__device__ __forceinline__ void cstore16(unsigned short* p, unsigned short v) {
    __hip_atomic_store(p, v, __ATOMIC_RELAXED, __HIP_MEMORY_SCOPE_AGENT);
}
__device__ __forceinline__ unsigned short cload16(const unsigned short* p) {
    return __hip_atomic_load(p, __ATOMIC_RELAXED, __HIP_MEMORY_SCOPE_AGENT);
}

#define MFMA(a, b, c) __builtin_amdgcn_mfma_f32_16x16x32_bf16((a), (b), (c), 0, 0, 0)

// Coherent A-load (L3), 16B, immediate byte offset.
#define LDA16(dst, base, imm) \
    asm volatile("global_load_dwordx4 %0, %1, off offset:%2 sc0 sc1" \
                 : "=v"(dst) : "v"(base), "i"(imm))
// Plain cached 16B load (x input).
#define LDX16(dst, base, imm) \
    asm volatile("global_load_dwordx4 %0, %1, off offset:%2" \
                 : "=v"(dst) : "v"(base), "i"(imm))
#define VWAIT(n) do { asm volatile("s_waitcnt vmcnt(" #n ")" ::: "memory"); \
                      __builtin_amdgcn_sched_barrier(0); } while (0)

__global__ void convert_w(const float* __restrict__ src, unsigned short* __restrict__ dst, int n) {
    int i = blockIdx.x * blockDim.x + threadIdx.x;
    int stride = gridDim.x * blockDim.x;
    for (; i < n; i += stride) dst[i] = f2bf(src[i]);
}

__global__ __launch_bounds__(512, 2) void gru_main(
    const float* __restrict__ x,
    const unsigned short* __restrict__ wih0,
    const unsigned short* __restrict__ whh0,
    const unsigned short* __restrict__ wih1,
    const unsigned short* __restrict__ whh1,
    const float* __restrict__ bih0, const float* __restrict__ bhh0,
    const float* __restrict__ bih1, const float* __restrict__ bhh1,
    const float* __restrict__ wfc,  const float* __restrict__ bfc,
    unsigned short* __restrict__ h0hi, unsigned short* __restrict__ h0lo,
    unsigned short* __restrict__ h1hi, unsigned short* __restrict__ h1lo,
    int* __restrict__ lvl0, int* __restrict__ lvl1, int* __restrict__ rel,
    float* __restrict__ out)
{
    const int wg    = blockIdx.x;
    const int layer = wg >> 7;           // 0 / 1
    const int cc    = wg & 127;          // 8-col chunk
    const int jb8   = cc << 3;
    const int tid   = threadIdx.x;
    const int wid   = tid >> 6;          // 0..7
    const int kh    = wid >> 2;          // K-half
    const int mw    = wid & 3;           // M-tile
    const int lane  = tid & 63;
    const int l15   = lane & 15;
    const int c8    = l15 & 7;           // real col (lanes 8-15 duplicate)
    const int kg8   = (lane >> 4) << 3;
    const int arow  = (mw << 4) + l15;
    const int kb    = kh << 9;           // recurrent K base (elements)
    const int ckb   = kh << 4;           // k-chunk base (chunks of 32)
    const int kbx   = kh << 7;           // L0 input K base

    const unsigned short* Whh = layer ? whh1 : whh0;
    const unsigned short* Wih = layer ? wih1 : wih0;
    const float* bih = layer ? bih1 : bih0;
    const float* bhh = layer ? bhh1 : bhh0;
    unsigned short* hhi = layer ? h1hi : h0hi;
    unsigned short* hlo = layer ? h1lo : h0lo;

    const int jg = jb8 + c8;

    const float bias_r  = bih[jg]        + bhh[jg];
    const float bias_z  = bih[HD + jg]   + bhh[HD + jg];
    const float bias_nx = bih[2*HD + jg];
    const float bias_nh = bhh[2*HD + jg];

    // W LDS: blocks of 512B = one k-chunk(32) x 8 cols; frag = [hi(4)][col(8)]x16B.
    __shared__ unsigned short wlds[192 * 256];   // 96KB
    __shared__ float part[16 * 4 * 64];          // 16KB K-half exchange
    __shared__ float red[256];

    if (layer == 1) {
        #pragma unroll
        for (int i = 0; i < 12; ++i) {
            int f = tid + i * 512;              // 0..6143
            int s   = f >> 10;
            int rem = f & 1023;
            int ck  = rem >> 5;
            int hi  = (rem >> 3) & 3;
            int c   = rem & 7;
            const unsigned short* src = (s < 3 ? Whh : Wih)
                + (size_t)((s % 3) * HD + jb8 + c) * HD + ck * 32 + hi * 8;
            *(short8*)(wlds + (s * 32 + ck) * 256 + hi * 64 + c * 8) =
                *(const short8*)src;
        }
    } else {
        #pragma unroll
        for (int i = 0; i < 6; ++i) {
            int f = tid + i * 512;              // 0..3071 (hh)
            int s   = f >> 10;
            int rem = f & 1023;
            int ck  = rem >> 5;
            int hi  = (rem >> 3) & 3;
            int c   = rem & 7;
            const unsigned short* src = Whh
                + (size_t)(s * HD + jb8 + c) * HD + ck * 32 + hi * 8;
            *(short8*)(wlds + (s * 32 + ck) * 256 + hi * 64 + c * 8) =
                *(const short8*)src;
        }
        for (int i = 0; i < 2; ++i) {           // f = 0..767 (ih) — full coverage
            int f = tid + i * 512;
            if (f < 768) {
                int s   = f >> 8;
                int rem = f & 255;
                int ck  = rem >> 5;
                int hi  = (rem >> 3) & 3;
                int c   = rem & 7;
                const unsigned short* src = Wih
                    + (size_t)(s * HD + jb8 + c) * IND + ck * 32 + hi * 8;
                *(short8*)(wlds + (96 + s * 8 + ck) * 256 + hi * 64 + c * 8) =
                    *(const short8*)src;
            }
        }
    }
    __syncthreads();

    const int lws = (lane >> 4) * 64 + c8 * 8;   // lane's frag offset in a block
#define LW(blk) (*(const short8*)(wlds + (blk) * 256 + lws))

    float hold[4] = {0.f, 0.f, 0.f, 0.f};   // kh0 threads' h cells (exact fp32)

    for (int iter = 0; iter <= TSEQ; ++iter) {
        const bool active = layer ? (iter >= 1) : (iter < TSEQ);
        if (active) {
            const int t     = layer ? (iter - 1) : iter;
            const int rs    = (t + 1) & 1;
            const int wslot = t & 1;
            const unsigned short* hrhi = hhi + rs * PL;
            const unsigned short* hrlo = hlo + rs * PL;
            const unsigned short* bAh = hrhi + (size_t)arow * HD + kb + kg8;
            const unsigned short* bAl = hrlo + (size_t)arow * HD + kb + kg8;

            f32x4 ar  = {0.f, 0.f, 0.f, 0.f};
            f32x4 az  = {0.f, 0.f, 0.f, 0.f};
            f32x4 ahn = {0.f, 0.f, 0.f, 0.f};
            f32x4 axn = {0.f, 0.f, 0.f, 0.f};

            if (layer == 0) {
                const float* px = x + ((size_t)arow * TSEQ + t) * IND + kbx + kg8;
                short8 Ah[5], Al[5], Wa[3], Wb[3];
#define L0A(c) do { LDA16(Ah[(c)%5], bAh, (c)*64); LDA16(Al[(c)%5], bAl, (c)*64); } while (0)
#define L0X(c) do { LDX16(Ah[(c)%5], px, ((c)-16)*128); LDX16(Al[(c)%5], px, ((c)-16)*128+16); } while (0)
#define WR0(c, WB) do { WB[0] = LW(ckb + (c)); WB[1] = LW(32 + ckb + (c)); \
                        WB[2] = LW(64 + ckb + (c)); } while (0)
#define WX0(c, WB) do { int xck = (ckb >> 2) + (c) - 16; \
                        WB[0] = LW(96 + xck); WB[1] = LW(104 + xck); \
                        WB[2] = LW(112 + xck); } while (0)
#define MR0(c, WB) do { \
    ar  = MFMA(Ah[(c)%5], WB[0], ar);  ar  = MFMA(Al[(c)%5], WB[0], ar);  \
    az  = MFMA(Ah[(c)%5], WB[1], az);  az  = MFMA(Al[(c)%5], WB[1], az);  \
    ahn = MFMA(Ah[(c)%5], WB[2], ahn); ahn = MFMA(Al[(c)%5], WB[2], ahn); } while (0)
#define MX0(c, WB) do { \
    float4 xa = __builtin_bit_cast(float4, Ah[(c)%5]); \
    float4 xc = __builtin_bit_cast(float4, Al[(c)%5]); \
    short8 af; \
    af[0] = (short)f2bf(xa.x); af[1] = (short)f2bf(xa.y); \
    af[2] = (short)f2bf(xa.z); af[3] = (short)f2bf(xa.w); \
    af[4] = (short)f2bf(xc.x); af[5] = (short)f2bf(xc.y); \
    af[6] = (short)f2bf(xc.z); af[7] = (short)f2bf(xc.w); \
    ar  = MFMA(af, WB[0], ar); \
    az  = MFMA(af, WB[1], az); \
    axn = MFMA(af, WB[2], axn); } while (0)
                WR0(0, Wa);
                L0A(0); L0A(1); L0A(2); L0A(3);
                WR0(1,  Wb); L0A(4);  VWAIT(8); MR0(0,  Wa);
                WR0(2,  Wa); L0A(5);  VWAIT(8); MR0(1,  Wb);
                WR0(3,  Wb); L0A(6);  VWAIT(8); MR0(2,  Wa);
                WR0(4,  Wa); L0A(7);  VWAIT(8); MR0(3,  Wb);
                WR0(5,  Wb); L0A(8);  VWAIT(8); MR0(4,  Wa);
                WR0(6,  Wa); L0A(9);  VWAIT(8); MR0(5,  Wb);
                WR0(7,  Wb); L0A(10); VWAIT(8); MR0(6,  Wa);
                WR0(8,  Wa); L0A(11); VWAIT(8); MR0(7,  Wb);
                WR0(9,  Wb); L0A(12); VWAIT(8); MR0(8,  Wa);
                WR0(10, Wa); L0A(13); VWAIT(8); MR0(9,  Wb);
                WR0(11, Wb); L0A(14); VWAIT(8); MR0(10, Wa);
                WR0(12, Wa); L0A(15); VWAIT(8); MR0(11, Wb);
                WR0(13, Wb); L0X(16); VWAIT(8); MR0(12, Wa);
                WR0(14, Wa); L0X(17); VWAIT(8); MR0(13, Wb);
                WR0(15, Wb); L0X(18); VWAIT(8); MR0(14, Wa);
                WX0(16, Wa); L0X(19); VWAIT(8); MR0(15, Wb);
                WX0(17, Wb); VWAIT(6); MX0(16, Wa);
                WX0(18, Wa); VWAIT(4); MX0(17, Wb);
                WX0(19, Wb); VWAIT(2); MX0(18, Wa);
                             VWAIT(0); MX0(19, Wb);
            } else {
                const unsigned short* bAy = h0hi + (size_t)wslot * PL
                                                 + (size_t)arow * HD + kb + kg8;
                short8 Ah[5], Al[5], Ay[5], Wa[6], Wb[6];
#define L1A(c) do { LDA16(Ah[(c)%5], bAh, (c)*64); LDA16(Al[(c)%5], bAl, (c)*64); \
                    LDA16(Ay[(c)%5], bAy, (c)*64); } while (0)
#define WR1(c, WB) do { WB[0] = LW(ckb + (c)); WB[1] = LW(32 + ckb + (c)); \
    WB[2] = LW(64 + ckb + (c)); WB[3] = LW(96 + ckb + (c)); \
    WB[4] = LW(128 + ckb + (c)); WB[5] = LW(160 + ckb + (c)); } while (0)
#define MF1(c, WB) do { \
    ar  = MFMA(Ah[(c)%5], WB[0], ar);  ar  = MFMA(Al[(c)%5], WB[0], ar);  \
    ar  = MFMA(Ay[(c)%5], WB[3], ar); \
    az  = MFMA(Ah[(c)%5], WB[1], az);  az  = MFMA(Al[(c)%5], WB[1], az);  \
    az  = MFMA(Ay[(c)%5], WB[4], az); \
    ahn = MFMA(Ah[(c)%5], WB[2], ahn); ahn = MFMA(Al[(c)%5], WB[2], ahn); \
    axn = MFMA(Ay[(c)%5], WB[5], axn); } while (0)
                WR1(0, Wa);
                L1A(0); L1A(1); L1A(2); L1A(3);
                WR1(1,  Wb); L1A(4);  VWAIT(12); MF1(0,  Wa);
                WR1(2,  Wa); L1A(5);  VWAIT(12); MF1(1,  Wb);
                WR1(3,  Wb); L1A(6);  VWAIT(12); MF1(2,  Wa);
                WR1(4,  Wa); L1A(7);  VWAIT(12); MF1(3,  Wb);
                WR1(5,  Wb); L1A(8);  VWAIT(12); MF1(4,  Wa);
                WR1(6,  Wa); L1A(9);  VWAIT(12); MF1(5,  Wb);
                WR1(7,  Wb); L1A(10); VWAIT(12); MF1(6,  Wa);
                WR1(8,  Wa); L1A(11); VWAIT(12); MF1(7,  Wb);
                WR1(9,  Wb); L1A(12); VWAIT(12); MF1(8,  Wa);
                WR1(10, Wa); L1A(13); VWAIT(12); MF1(9,  Wb);
                WR1(11, Wb); L1A(14); VWAIT(12); MF1(10, Wa);
                WR1(12, Wa); L1A(15); VWAIT(12); MF1(11, Wb);
                WR1(13, Wb); VWAIT(9); MF1(12, Wa);
                WR1(14, Wa); VWAIT(6); MF1(13, Wb);
                WR1(15, Wb); VWAIT(3); MF1(14, Wa);
                             VWAIT(0); MF1(15, Wb);
            }

            // ---- K-half combine in LDS; gates + h store on kh0 waves ----
            if (kh) {
                #pragma unroll
                for (int e = 0; e < 4; ++e) {
                    part[((0*4 + e) * 4 + mw) * 64 + lane] = ar[e];
                    part[((1*4 + e) * 4 + mw) * 64 + lane] = az[e];
                    part[((2*4 + e) * 4 + mw) * 64 + lane] = ahn[e];
                    part[((3*4 + e) * 4 + mw) * 64 + lane] = axn[e];
                }
            }
            __syncthreads();
            if (!kh) {
                unsigned short* hwhi = hhi + wslot * PL;
                unsigned short* hwlo = hlo + wslot * PL;
                #pragma unroll
                for (int e = 0; e < 4; ++e) {
                    const float arr = ar[e]  + part[((0*4 + e) * 4 + mw) * 64 + lane];
                    const float azz = az[e]  + part[((1*4 + e) * 4 + mw) * 64 + lane];
                    const float ahh = ahn[e] + part[((2*4 + e) * 4 + mw) * 64 + lane];
                    const float axx = axn[e] + part[((3*4 + e) * 4 + mw) * 64 + lane];
                    const int bat = (mw << 4) + ((lane >> 4) << 2) + e;
                    const size_t idx = (size_t)bat * HD + jg;
                    float r = sigm(arr + bias_r);
                    float z = sigm(azz + bias_z);
                    float n = tanh_fast(axx + bias_nx + r * (ahh + bias_nh));
                    float hnew = (1.0f - z) * n + z * hold[e];
                    hold[e] = hnew;
                    if (l15 < 8) {
                        unsigned short hi_ = f2bf(hnew);
                        cstore16(hwhi + idx, hi_);
                        cstore16(hwlo + idx, f2bf(hnew - bf2f((unsigned)hi_)));
                    }
                }
            }
        }

        // ---- tree barrier: 32 groups x 8 WGs -> root -> 32 release lines ----
        asm volatile("s_waitcnt vmcnt(0)" ::: "memory");   // h stores at L3
        __syncthreads();
        if (tid == 0) {
            const int g = wg >> 3;
            int* l0p = lvl0 + ((size_t)iter * 32 + g) * FS;
            int old = __hip_atomic_fetch_add(l0p, 1, __ATOMIC_RELAXED,
                                             __HIP_MEMORY_SCOPE_AGENT);
            if (old == 7) {                       // last of group -> leader
                int old2 = __hip_atomic_fetch_add(lvl1 + (size_t)iter * FS, 1,
                                                  __ATOMIC_RELAXED,
                                                  __HIP_MEMORY_SCOPE_AGENT);
                if (old2 == 31) {                 // last leader -> root
                    #pragma unroll
                    for (int k = 0; k < 32; ++k)
                        __hip_atomic_store(rel + ((size_t)iter * 32 + k) * FS, 1,
                                           __ATOMIC_RELAXED,
                                           __HIP_MEMORY_SCOPE_AGENT);
                }
            }
            int* rp = rel + ((size_t)iter * 32 + g) * FS;
            int spins = 0;
            while (__hip_atomic_load(rp, __ATOMIC_RELAXED,
                                     __HIP_MEMORY_SCOPE_AGENT) < 1) {
                __builtin_amdgcn_s_sleep(2);
                if (++spins > (1 << 20)) break;   // fail loud, never hang
            }
        }
        __syncthreads();
    }

    // ---- deterministic FC tail (single WG, coherent reads) ----
    if (wg == 0) {
        const int fslot = (TSEQ - 1) & 1;
        const unsigned short* hf_hi = h1hi + (size_t)fslot * PL;
        const unsigned short* hf_lo = h1lo + (size_t)fslot * PL;
        if (tid < 256) {
            const int bat  = tid & 63;
            const int pidx = tid >> 6;
            const int k0   = pidx * (HD / 4);
            float s = 0.0f;
            for (int k = 0; k < HD / 4; ++k) {
                size_t idx = (size_t)bat * HD + k0 + k;
                s += (bf2f((unsigned)cload16(hf_hi + idx)) +
                      bf2f((unsigned)cload16(hf_lo + idx))) * wfc[k0 + k];
            }
            red[tid] = s;
        }
        __syncthreads();
        if (tid < 64)
            out[tid] = red[tid] + red[tid + 64] + red[tid + 128] + red[tid + 192] + bfc[0];
    }
}

extern "C" void kernel_launch(void* const* d_in, const int* in_sizes, int n_in,
                              void* d_out, int out_size, void* d_ws, size_t ws_size,
                              hipStream_t stream) {
    const float* x    = (const float*)d_in[0];
    const float* Wih0 = (const float*)d_in[1];
    const float* Whh0 = (const float*)d_in[2];
    const float* bih0 = (const float*)d_in[3];
    const float* bhh0 = (const float*)d_in[4];
    const float* Wih1 = (const float*)d_in[5];
    const float* Whh1 = (const float*)d_in[6];
    const float* bih1 = (const float*)d_in[7];
    const float* bhh1 = (const float*)d_in[8];
    const float* Wfc  = (const float*)d_in[9];
    const float* bfc  = (const float*)d_in[10];
    float* out = (float*)d_out;

    char* ws = (char*)d_ws;
    size_t off = 0;
    int* lvl0 = (int*)(ws + off); off += (size_t)(TSEQ + 1) * 32 * FS * 4;
    int* lvl1 = (int*)(ws + off); off += (size_t)(TSEQ + 1) * FS * 4;
    int* rel  = (int*)(ws + off); off += (size_t)(TSEQ + 1) * 32 * FS * 4;
    unsigned short* h0hi = (unsigned short*)(ws + off); off += (size_t)2 * PL * 2;
    unsigned short* h0lo = (unsigned short*)(ws + off); off += (size_t)2 * PL * 2;
    unsigned short* h1hi = (unsigned short*)(ws + off); off += (size_t)2 * PL * 2;
    unsigned short* h1lo = (unsigned short*)(ws + off); off += (size_t)2 * PL * 2;
    size_t zero_bytes = off;
    unsigned short* wih0b = (unsigned short*)(ws + off); off += (size_t)3 * HD * IND * 2;
    unsigned short* whh0b = (unsigned short*)(ws + off); off += (size_t)3 * HD * HD * 2;
    unsigned short* wih1b = (unsigned short*)(ws + off); off += (size_t)3 * HD * HD * 2;
    unsigned short* whh1b = (unsigned short*)(ws + off); off += (size_t)3 * HD * HD * 2;
    if (off > ws_size) return;   // loud validation failure

    hipMemsetAsync(d_ws, 0, zero_bytes, stream);
    hipMemsetAsync(d_out, 0, (size_t)out_size * sizeof(float), stream);

    convert_w<<<512, 256, 0, stream>>>(Wih0, wih0b, 3 * HD * IND);
    convert_w<<<512, 256, 0, stream>>>(Whh0, whh0b, 3 * HD * HD);
    convert_w<<<512, 256, 0, stream>>>(Wih1, wih1b, 3 * HD * HD);
    convert_w<<<512, 256, 0, stream>>>(Whh1, whh1b, 3 * HD * HD);

    gru_main<<<NWG, 512, 0, stream>>>(x, wih0b, whh0b, wih1b, whh1b,
                                      bih0, bhh0, bih1, bhh1, Wfc, bfc,
                                      h0hi, h0lo, h1hi, h1lo,
                                      lvl0, lvl1, rel, out);
}

// Round 14
// 7093.591 us; speedup vs baseline: 1.3912x; 1.0020x over previous
//
#include <hip/hip_runtime.h>
#include <hip/hip_bf16.h>
#include <stdint.h>

// ---------------------------------------------------------------------------
// 2-layer GRU (B=64,T=512,IN=256,H=1024) + FC, fp32 I/O.
// R14 = R13 (PASSED, 7.11ms) with ONE change: A-prefetch ring deepened 5 -> 8
// (7 bodies ahead, 21-24 loads in flight per wave). Tests the hypothesis that
// the ~6-8us/iter unexplained stall is A-load LATENCY under full-chip
// contention (R12 ruled out bandwidth; ring-4-deep covers only ~latency/4).
// Tree barrier (R13), W-in-LDS (R9), in-WG K-split (R9) unchanged.
// Precision: W bf16, h as bf16 hi+lo planes, gates fp32.
// ---------------------------------------------------------------------------

constexpr int TSEQ = 512;
constexpr int NB   = 64;
constexpr int HD   = 1024;
constexpr int IND  = 256;
constexpr int NWG  = 256;
constexpr int FS   = 16;            // counter stride in ints (64B lines)
constexpr int PL   = NB * HD;       // elements per h plane

typedef float f32x4  __attribute__((ext_vector_type(4)));
typedef short short8 __attribute__((ext_vector_type(8)));

__device__ __forceinline__ float bf2f(unsigned u) {
    return __builtin_bit_cast(float, u << 16);
}
__device__ __forceinline__ unsigned short f2bf(float f) {
    unsigned u = __builtin_bit_cast(unsigned, f);
    u += 0x7fffu + ((u >> 16) & 1u);     // RNE
    return (unsigned short)(u >> 16);
}
__device__ __forceinline__ float sigm(float x) { return 1.0f / (1.0f + __expf(-x)); }
__device__ __forceinline__ float tanh_fast(float x) { return 1.0f - 2.0f / (1.0f + __expf(2.0f * x)); }

__device__ __forceinline__ void cstore16(unsigned short* p, unsigned short v) {
    __hip_atomic_store(p, v, __ATOMIC_RELAXED, __HIP_MEMORY_SCOPE_AGENT);
}
__device__ __forceinline__ unsigned short cload16(const unsigned short* p) {
    return __hip_atomic_load(p, __ATOMIC_RELAXED, __HIP_MEMORY_SCOPE_AGENT);
}

#define MFMA(a, b, c) __builtin_amdgcn_mfma_f32_16x16x32_bf16((a), (b), (c), 0, 0, 0)

// Coherent A-load (L3), 16B, immediate byte offset.
#define LDA16(dst, base, imm) \
    asm volatile("global_load_dwordx4 %0, %1, off offset:%2 sc0 sc1" \
                 : "=v"(dst) : "v"(base), "i"(imm))
// Plain cached 16B load (x input).
#define LDX16(dst, base, imm) \
    asm volatile("global_load_dwordx4 %0, %1, off offset:%2" \
                 : "=v"(dst) : "v"(base), "i"(imm))
#define VWAIT(n) do { asm volatile("s_waitcnt vmcnt(" #n ")" ::: "memory"); \
                      __builtin_amdgcn_sched_barrier(0); } while (0)

__global__ void convert_w(const float* __restrict__ src, unsigned short* __restrict__ dst, int n) {
    int i = blockIdx.x * blockDim.x + threadIdx.x;
    int stride = gridDim.x * blockDim.x;
    for (; i < n; i += stride) dst[i] = f2bf(src[i]);
}

__global__ __launch_bounds__(512, 2) void gru_main(
    const float* __restrict__ x,
    const unsigned short* __restrict__ wih0,
    const unsigned short* __restrict__ whh0,
    const unsigned short* __restrict__ wih1,
    const unsigned short* __restrict__ whh1,
    const float* __restrict__ bih0, const float* __restrict__ bhh0,
    const float* __restrict__ bih1, const float* __restrict__ bhh1,
    const float* __restrict__ wfc,  const float* __restrict__ bfc,
    unsigned short* __restrict__ h0hi, unsigned short* __restrict__ h0lo,
    unsigned short* __restrict__ h1hi, unsigned short* __restrict__ h1lo,
    int* __restrict__ lvl0, int* __restrict__ lvl1, int* __restrict__ rel,
    float* __restrict__ out)
{
    const int wg    = blockIdx.x;
    const int layer = wg >> 7;           // 0 / 1
    const int cc    = wg & 127;          // 8-col chunk
    const int jb8   = cc << 3;
    const int tid   = threadIdx.x;
    const int wid   = tid >> 6;          // 0..7
    const int kh    = wid >> 2;          // K-half
    const int mw    = wid & 3;           // M-tile
    const int lane  = tid & 63;
    const int l15   = lane & 15;
    const int c8    = l15 & 7;           // real col (lanes 8-15 duplicate)
    const int kg8   = (lane >> 4) << 3;
    const int arow  = (mw << 4) + l15;
    const int kb    = kh << 9;           // recurrent K base (elements)
    const int ckb   = kh << 4;           // k-chunk base (chunks of 32)
    const int kbx   = kh << 7;           // L0 input K base

    const unsigned short* Whh = layer ? whh1 : whh0;
    const unsigned short* Wih = layer ? wih1 : wih0;
    const float* bih = layer ? bih1 : bih0;
    const float* bhh = layer ? bhh1 : bhh0;
    unsigned short* hhi = layer ? h1hi : h0hi;
    unsigned short* hlo = layer ? h1lo : h0lo;

    const int jg = jb8 + c8;

    const float bias_r  = bih[jg]        + bhh[jg];
    const float bias_z  = bih[HD + jg]   + bhh[HD + jg];
    const float bias_nx = bih[2*HD + jg];
    const float bias_nh = bhh[2*HD + jg];

    // W LDS: blocks of 512B = one k-chunk(32) x 8 cols; frag = [hi(4)][col(8)]x16B.
    __shared__ unsigned short wlds[192 * 256];   // 96KB
    __shared__ float part[16 * 4 * 64];          // 16KB K-half exchange
    __shared__ float red[256];

    if (layer == 1) {
        #pragma unroll
        for (int i = 0; i < 12; ++i) {
            int f = tid + i * 512;              // 0..6143
            int s   = f >> 10;
            int rem = f & 1023;
            int ck  = rem >> 5;
            int hi  = (rem >> 3) & 3;
            int c   = rem & 7;
            const unsigned short* src = (s < 3 ? Whh : Wih)
                + (size_t)((s % 3) * HD + jb8 + c) * HD + ck * 32 + hi * 8;
            *(short8*)(wlds + (s * 32 + ck) * 256 + hi * 64 + c * 8) =
                *(const short8*)src;
        }
    } else {
        #pragma unroll
        for (int i = 0; i < 6; ++i) {
            int f = tid + i * 512;              // 0..3071 (hh)
            int s   = f >> 10;
            int rem = f & 1023;
            int ck  = rem >> 5;
            int hi  = (rem >> 3) & 3;
            int c   = rem & 7;
            const unsigned short* src = Whh
                + (size_t)(s * HD + jb8 + c) * HD + ck * 32 + hi * 8;
            *(short8*)(wlds + (s * 32 + ck) * 256 + hi * 64 + c * 8) =
                *(const short8*)src;
        }
        for (int i = 0; i < 2; ++i) {           // f = 0..767 (ih) — full coverage
            int f = tid + i * 512;
            if (f < 768) {
                int s   = f >> 8;
                int rem = f & 255;
                int ck  = rem >> 5;
                int hi  = (rem >> 3) & 3;
                int c   = rem & 7;
                const unsigned short* src = Wih
                    + (size_t)(s * HD + jb8 + c) * IND + ck * 32 + hi * 8;
                *(short8*)(wlds + (96 + s * 8 + ck) * 256 + hi * 64 + c * 8) =
                    *(const short8*)src;
            }
        }
    }
    __syncthreads();

    const int lws = (lane >> 4) * 64 + c8 * 8;   // lane's frag offset in a block
#define LW(blk) (*(const short8*)(wlds + (blk) * 256 + lws))

    float hold[4] = {0.f, 0.f, 0.f, 0.f};   // kh0 threads' h cells (exact fp32)

    for (int iter = 0; iter <= TSEQ; ++iter) {
        const bool active = layer ? (iter >= 1) : (iter < TSEQ);
        if (active) {
            const int t     = layer ? (iter - 1) : iter;
            const int rs    = (t + 1) & 1;
            const int wslot = t & 1;
            const unsigned short* hrhi = hhi + rs * PL;
            const unsigned short* hrlo = hlo + rs * PL;
            const unsigned short* bAh = hrhi + (size_t)arow * HD + kb + kg8;
            const unsigned short* bAl = hrlo + (size_t)arow * HD + kb + kg8;

            f32x4 ar  = {0.f, 0.f, 0.f, 0.f};
            f32x4 az  = {0.f, 0.f, 0.f, 0.f};
            f32x4 ahn = {0.f, 0.f, 0.f, 0.f};
            f32x4 axn = {0.f, 0.f, 0.f, 0.f};

            if (layer == 0) {
                const float* px = x + ((size_t)arow * TSEQ + t) * IND + kbx + kg8;
                short8 Ah[8], Al[8], Wa[3], Wb[3];
#define L0A(c) do { LDA16(Ah[(c)%8], bAh, (c)*64); LDA16(Al[(c)%8], bAl, (c)*64); } while (0)
#define L0X(c) do { LDX16(Ah[(c)%8], px, ((c)-16)*128); LDX16(Al[(c)%8], px, ((c)-16)*128+16); } while (0)
#define WR0(c, WB) do { WB[0] = LW(ckb + (c)); WB[1] = LW(32 + ckb + (c)); \
                        WB[2] = LW(64 + ckb + (c)); } while (0)
#define WX0(c, WB) do { int xck = (ckb >> 2) + (c) - 16; \
                        WB[0] = LW(96 + xck); WB[1] = LW(104 + xck); \
                        WB[2] = LW(112 + xck); } while (0)
#define MR0(c, WB) do { \
    ar  = MFMA(Ah[(c)%8], WB[0], ar);  ar  = MFMA(Al[(c)%8], WB[0], ar);  \
    az  = MFMA(Ah[(c)%8], WB[1], az);  az  = MFMA(Al[(c)%8], WB[1], az);  \
    ahn = MFMA(Ah[(c)%8], WB[2], ahn); ahn = MFMA(Al[(c)%8], WB[2], ahn); } while (0)
#define MX0(c, WB) do { \
    float4 xa = __builtin_bit_cast(float4, Ah[(c)%8]); \
    float4 xc = __builtin_bit_cast(float4, Al[(c)%8]); \
    short8 af; \
    af[0] = (short)f2bf(xa.x); af[1] = (short)f2bf(xa.y); \
    af[2] = (short)f2bf(xa.z); af[3] = (short)f2bf(xa.w); \
    af[4] = (short)f2bf(xc.x); af[5] = (short)f2bf(xc.y); \
    af[6] = (short)f2bf(xc.z); af[7] = (short)f2bf(xc.w); \
    ar  = MFMA(af, WB[0], ar); \
    az  = MFMA(af, WB[1], az); \
    axn = MFMA(af, WB[2], axn); } while (0)
                WR0(0, Wa);
                L0A(0); L0A(1); L0A(2); L0A(3); L0A(4); L0A(5); L0A(6);
                WR0(1,  Wb); L0A(7);  VWAIT(14); MR0(0,  Wa);
                WR0(2,  Wa); L0A(8);  VWAIT(14); MR0(1,  Wb);
                WR0(3,  Wb); L0A(9);  VWAIT(14); MR0(2,  Wa);
                WR0(4,  Wa); L0A(10); VWAIT(14); MR0(3,  Wb);
                WR0(5,  Wb); L0A(11); VWAIT(14); MR0(4,  Wa);
                WR0(6,  Wa); L0A(12); VWAIT(14); MR0(5,  Wb);
                WR0(7,  Wb); L0A(13); VWAIT(14); MR0(6,  Wa);
                WR0(8,  Wa); L0A(14); VWAIT(14); MR0(7,  Wb);
                WR0(9,  Wb); L0A(15); VWAIT(14); MR0(8,  Wa);
                WR0(10, Wa); L0X(16); VWAIT(14); MR0(9,  Wb);
                WR0(11, Wb); L0X(17); VWAIT(14); MR0(10, Wa);
                WR0(12, Wa); L0X(18); VWAIT(14); MR0(11, Wb);
                WR0(13, Wb); L0X(19); VWAIT(14); MR0(12, Wa);
                WR0(14, Wa);          VWAIT(12); MR0(13, Wb);
                WR0(15, Wb);          VWAIT(10); MR0(14, Wa);
                WX0(16, Wa);          VWAIT(8);  MR0(15, Wb);
                WX0(17, Wb);          VWAIT(6);  MX0(16, Wa);
                WX0(18, Wa);          VWAIT(4);  MX0(17, Wb);
                WX0(19, Wb);          VWAIT(2);  MX0(18, Wa);
                                      VWAIT(0);  MX0(19, Wb);
            } else {
                const unsigned short* bAy = h0hi + (size_t)wslot * PL
                                                 + (size_t)arow * HD + kb + kg8;
                short8 Ah[8], Al[8], Ay[8], Wa[6], Wb[6];
#define L1A(c) do { LDA16(Ah[(c)%8], bAh, (c)*64); LDA16(Al[(c)%8], bAl, (c)*64); \
                    LDA16(Ay[(c)%8], bAy, (c)*64); } while (0)
#define WR1(c, WB) do { WB[0] = LW(ckb + (c)); WB[1] = LW(32 + ckb + (c)); \
    WB[2] = LW(64 + ckb + (c)); WB[3] = LW(96 + ckb + (c)); \
    WB[4] = LW(128 + ckb + (c)); WB[5] = LW(160 + ckb + (c)); } while (0)
#define MF1(c, WB) do { \
    ar  = MFMA(Ah[(c)%8], WB[0], ar);  ar  = MFMA(Al[(c)%8], WB[0], ar);  \
    ar  = MFMA(Ay[(c)%8], WB[3], ar); \
    az  = MFMA(Ah[(c)%8], WB[1], az);  az  = MFMA(Al[(c)%8], WB[1], az);  \
    az  = MFMA(Ay[(c)%8], WB[4], az); \
    ahn = MFMA(Ah[(c)%8], WB[2], ahn); ahn = MFMA(Al[(c)%8], WB[2], ahn); \
    axn = MFMA(Ay[(c)%8], WB[5], axn); } while (0)
                WR1(0, Wa);
                L1A(0); L1A(1); L1A(2); L1A(3); L1A(4); L1A(5); L1A(6);
                WR1(1,  Wb); L1A(7);  VWAIT(21); MF1(0,  Wa);
                WR1(2,  Wa); L1A(8);  VWAIT(21); MF1(1,  Wb);
                WR1(3,  Wb); L1A(9);  VWAIT(21); MF1(2,  Wa);
                WR1(4,  Wa); L1A(10); VWAIT(21); MF1(3,  Wb);
                WR1(5,  Wb); L1A(11); VWAIT(21); MF1(4,  Wa);
                WR1(6,  Wa); L1A(12); VWAIT(21); MF1(5,  Wb);
                WR1(7,  Wb); L1A(13); VWAIT(21); MF1(6,  Wa);
                WR1(8,  Wa); L1A(14); VWAIT(21); MF1(7,  Wb);
                WR1(9,  Wb); L1A(15); VWAIT(21); MF1(8,  Wa);
                WR1(10, Wa);          VWAIT(18); MF1(9,  Wb);
                WR1(11, Wb);          VWAIT(15); MF1(10, Wa);
                WR1(12, Wa);          VWAIT(12); MF1(11, Wb);
                WR1(13, Wb);          VWAIT(9);  MF1(12, Wa);
                WR1(14, Wa);          VWAIT(6);  MF1(13, Wb);
                WR1(15, Wb);          VWAIT(3);  MF1(14, Wa);
                                      VWAIT(0);  MF1(15, Wb);
            }

            // ---- K-half combine in LDS; gates + h store on kh0 waves ----
            if (kh) {
                #pragma unroll
                for (int e = 0; e < 4; ++e) {
                    part[((0*4 + e) * 4 + mw) * 64 + lane] = ar[e];
                    part[((1*4 + e) * 4 + mw) * 64 + lane] = az[e];
                    part[((2*4 + e) * 4 + mw) * 64 + lane] = ahn[e];
                    part[((3*4 + e) * 4 + mw) * 64 + lane] = axn[e];
                }
            }
            __syncthreads();
            if (!kh) {
                unsigned short* hwhi = hhi + wslot * PL;
                unsigned short* hwlo = hlo + wslot * PL;
                #pragma unroll
                for (int e = 0; e < 4; ++e) {
                    const float arr = ar[e]  + part[((0*4 + e) * 4 + mw) * 64 + lane];
                    const float azz = az[e]  + part[((1*4 + e) * 4 + mw) * 64 + lane];
                    const float ahh = ahn[e] + part[((2*4 + e) * 4 + mw) * 64 + lane];
                    const float axx = axn[e] + part[((3*4 + e) * 4 + mw) * 64 + lane];
                    const int bat = (mw << 4) + ((lane >> 4) << 2) + e;
                    const size_t idx = (size_t)bat * HD + jg;
                    float r = sigm(arr + bias_r);
                    float z = sigm(azz + bias_z);
                    float n = tanh_fast(axx + bias_nx + r * (ahh + bias_nh));
                    float hnew = (1.0f - z) * n + z * hold[e];
                    hold[e] = hnew;
                    if (l15 < 8) {
                        unsigned short hi_ = f2bf(hnew);
                        cstore16(hwhi + idx, hi_);
                        cstore16(hwlo + idx, f2bf(hnew - bf2f((unsigned)hi_)));
                    }
                }
            }
        }

        // ---- tree barrier: 32 groups x 8 WGs -> root -> 32 release lines ----
        asm volatile("s_waitcnt vmcnt(0)" ::: "memory");   // h stores at L3
        __syncthreads();
        if (tid == 0) {
            const int g = wg >> 3;
            int* l0p = lvl0 + ((size_t)iter * 32 + g) * FS;
            int old = __hip_atomic_fetch_add(l0p, 1, __ATOMIC_RELAXED,
                                             __HIP_MEMORY_SCOPE_AGENT);
            if (old == 7) {                       // last of group -> leader
                int old2 = __hip_atomic_fetch_add(lvl1 + (size_t)iter * FS, 1,
                                                  __ATOMIC_RELAXED,
                                                  __HIP_MEMORY_SCOPE_AGENT);
                if (old2 == 31) {                 // last leader -> root
                    #pragma unroll
                    for (int k = 0; k < 32; ++k)
                        __hip_atomic_store(rel + ((size_t)iter * 32 + k) * FS, 1,
                                           __ATOMIC_RELAXED,
                                           __HIP_MEMORY_SCOPE_AGENT);
                }
            }
            int* rp = rel + ((size_t)iter * 32 + g) * FS;
            int spins = 0;
            while (__hip_atomic_load(rp, __ATOMIC_RELAXED,
                                     __HIP_MEMORY_SCOPE_AGENT) < 1) {
                __builtin_amdgcn_s_sleep(2);
                if (++spins > (1 << 20)) break;   // fail loud, never hang
            }
        }
        __syncthreads();
    }

    // ---- deterministic FC tail (single WG, coherent reads) ----
    if (wg == 0) {
        const int fslot = (TSEQ - 1) & 1;
        const unsigned short* hf_hi = h1hi + (size_t)fslot * PL;
        const unsigned short* hf_lo = h1lo + (size_t)fslot * PL;
        if (tid < 256) {
            const int bat  = tid & 63;
            const int pidx = tid >> 6;
            const int k0   = pidx * (HD / 4);
            float s = 0.0f;
            for (int k = 0; k < HD / 4; ++k) {
                size_t idx = (size_t)bat * HD + k0 + k;
                s += (bf2f((unsigned)cload16(hf_hi + idx)) +
                      bf2f((unsigned)cload16(hf_lo + idx))) * wfc[k0 + k];
            }
            red[tid] = s;
        }
        __syncthreads();
        if (tid < 64)
            out[tid] = red[tid] + red[tid + 64] + red[tid + 128] + red[tid + 192] + bfc[0];
    }
}

extern "C" void kernel_launch(void* const* d_in, const int* in_sizes, int n_in,
                              void* d_out, int out_size, void* d_ws, size_t ws_size,
                              hipStream_t stream) {
    const float* x    = (const float*)d_in[0];
    const float* Wih0 = (const float*)d_in[1];
    const float* Whh0 = (const float*)d_in[2];
    const float* bih0 = (const float*)d_in[3];
    const float* bhh0 = (const float*)d_in[4];
    const float* Wih1 = (const float*)d_in[5];
    const float* Whh1 = (const float*)d_in[6];
    const float* bih1 = (const float*)d_in[7];
    const float* bhh1 = (const float*)d_in[8];
    const float* Wfc  = (const float*)d_in[9];
    const float* bfc  = (const float*)d_in[10];
    float* out = (float*)d_out;

    char* ws = (char*)d_ws;
    size_t off = 0;
    int* lvl0 = (int*)(ws + off); off += (size_t)(TSEQ + 1) * 32 * FS * 4;
    int* lvl1 = (int*)(ws + off); off += (size_t)(TSEQ + 1) * FS * 4;
    int* rel  = (int*)(ws + off); off += (size_t)(TSEQ + 1) * 32 * FS * 4;
    unsigned short* h0hi = (unsigned short*)(ws + off); off += (size_t)2 * PL * 2;
    unsigned short* h0lo = (unsigned short*)(ws + off); off += (size_t)2 * PL * 2;
    unsigned short* h1hi = (unsigned short*)(ws + off); off += (size_t)2 * PL * 2;
    unsigned short* h1lo = (unsigned short*)(ws + off); off += (size_t)2 * PL * 2;
    size_t zero_bytes = off;
    unsigned short* wih0b = (unsigned short*)(ws + off); off += (size_t)3 * HD * IND * 2;
    unsigned short* whh0b = (unsigned short*)(ws + off); off += (size_t)3 * HD * HD * 2;
    unsigned short* wih1b = (unsigned short*)(ws + off); off += (size_t)3 * HD * HD * 2;
    unsigned short* whh1b = (unsigned short*)(ws + off); off += (size_t)3 * HD * HD * 2;
    if (off > ws_size) return;   // loud validation failure

    hipMemsetAsync(d_ws, 0, zero_bytes, stream);
    hipMemsetAsync(d_out, 0, (size_t)out_size * sizeof(float), stream);

    convert_w<<<512, 256, 0, stream>>>(Wih0, wih0b, 3 * HD * IND);
    convert_w<<<512, 256, 0, stream>>>(Whh0, whh0b, 3 * HD * HD);
    convert_w<<<512, 256, 0, stream>>>(Wih1, wih1b, 3 * HD * HD);
    convert_w<<<512, 256, 0, stream>>>(Whh1, whh1b, 3 * HD * HD);

    gru_main<<<NWG, 512, 0, stream>>>(x, wih0b, whh0b, wih1b, whh1b,
                                      bih0, bhh0, bih1, bhh1, Wfc, bfc,
                                      h0hi, h0lo, h1hi, h1lo,
                                      lvl0, lvl1, rel, out);
}